// Round 1
// baseline (371.948 us; speedup 1.0000x reference)
//
#include <hip/hip_runtime.h>

// FrequencyDecomposition: blocked 8x8 DCT -> zigzag band masking -> blocked
// "inverse" (the reference einsum actually applies D . W . D^T again, NOT
// D^T W D -- we replicate the einsum exactly).
//
// x: [32, 3, 512, 512] fp32 -> out: [3, 32, 3, 512, 512] fp32
// One thread handles one 8x8 block entirely in registers; fully unrolled so
// the constexpr DCT matrix and band masks fold into immediates and the
// 16-coefficient low/high bands drop their zero terms at compile time.

namespace {

// Orthonormal DCT-II matrix, row k, col i = sqrt(2/8)*cos(pi*k*(2i+1)/16),
// row 0 = 1/sqrt(8). float64-accurate literals rounded to fp32.
constexpr float DM[8][8] = {
  { 0.35355339059327373f, 0.35355339059327373f, 0.35355339059327373f, 0.35355339059327373f,
    0.35355339059327373f, 0.35355339059327373f, 0.35355339059327373f, 0.35355339059327373f },
  { 0.49039264020161522f, 0.41573480615127262f, 0.27778511650980114f, 0.09754516100806417f,
   -0.09754516100806417f,-0.27778511650980114f,-0.41573480615127262f,-0.49039264020161522f },
  { 0.46193976625564337f, 0.19134171618254492f,-0.19134171618254492f,-0.46193976625564337f,
   -0.46193976625564337f,-0.19134171618254492f, 0.19134171618254492f, 0.46193976625564337f },
  { 0.41573480615127262f,-0.09754516100806417f,-0.49039264020161522f,-0.27778511650980114f,
    0.27778511650980114f, 0.49039264020161522f, 0.09754516100806417f,-0.41573480615127262f },
  { 0.35355339059327373f,-0.35355339059327373f,-0.35355339059327373f, 0.35355339059327373f,
    0.35355339059327373f,-0.35355339059327373f,-0.35355339059327373f, 0.35355339059327373f },
  { 0.27778511650980114f,-0.49039264020161522f, 0.09754516100806417f, 0.41573480615127262f,
   -0.41573480615127262f,-0.09754516100806417f, 0.49039264020161522f,-0.27778511650980114f },
  { 0.19134171618254492f,-0.46193976625564337f, 0.46193976625564337f,-0.19134171618254492f,
   -0.19134171618254492f, 0.46193976625564337f,-0.46193976625564337f, 0.19134171618254492f },
  { 0.09754516100806417f,-0.27778511650980114f, 0.41573480615127262f,-0.49039264020161522f,
    0.49039264020161522f,-0.41573480615127262f, 0.27778511650980114f,-0.09754516100806417f }
};

// Standard JPEG zigzag index of coefficient (k,l) -- matches the reference's
// _zigzag_indices generator.
constexpr int ZZ[8][8] = {
  { 0,  1,  5,  6, 14, 15, 27, 28},
  { 2,  4,  7, 13, 16, 26, 29, 42},
  { 3,  8, 12, 17, 25, 30, 41, 43},
  { 9, 11, 18, 24, 31, 40, 44, 53},
  {10, 19, 23, 32, 39, 45, 52, 54},
  {20, 22, 33, 38, 46, 51, 55, 60},
  {21, 34, 37, 47, 50, 56, 59, 61},
  {35, 36, 48, 49, 57, 58, 62, 63}
};

// band 0 = low (z < 16), band 2 = high (z >= 48), band 1 = mid.
constexpr int band_of(int k, int l) {
  return ZZ[k][l] < 16 ? 0 : (ZZ[k][l] >= 48 ? 2 : 1);
}

} // namespace

// Geometry constants for x: [B=32, C=3, H=512, W=512], 8x8 blocks.
//   images (B*C) = 96, each 512*512 = 262144 floats
//   block grid per image: 64 x 64
__global__ __launch_bounds__(256) void freq_decomp_kernel(
    const float* __restrict__ x, float* __restrict__ out) {
  const int tid = blockIdx.x * 256 + threadIdx.x;   // 0 .. 393215, exact grid
  const int wb = tid & 63;          // block col
  const int hb = (tid >> 6) & 63;   // block row
  const int bc = tid >> 12;         // image index 0..95 (b*3 + c)

  const float* in = x + ((size_t)bc << 18) + (size_t)hb * 4096 + wb * 8;

  // ---- load 8x8 block (coalesced: adjacent lanes take adjacent blocks) ----
  float X[8][8];
#pragma unroll
  for (int r = 0; r < 8; ++r) {
    const float4 a = *(const float4*)(in + (size_t)r * 512);
    const float4 b = *(const float4*)(in + (size_t)r * 512 + 4);
    X[r][0] = a.x; X[r][1] = a.y; X[r][2] = a.z; X[r][3] = a.w;
    X[r][4] = b.x; X[r][5] = b.y; X[r][6] = b.z; X[r][7] = b.w;
  }

  // ---- forward: T = D . X . D^T ----
  // V[i][c] = sum_j X[i][j] * DM[c][j]   (X . D^T)
  float V[8][8];
#pragma unroll
  for (int i = 0; i < 8; ++i) {
#pragma unroll
    for (int c = 0; c < 8; ++c) {
      float s = 0.0f;
#pragma unroll
      for (int j = 0; j < 8; ++j) s = fmaf(X[i][j], DM[c][j], s);
      V[i][c] = s;
    }
  }
  // T[k][l] = sum_i DM[k][i] * V[i][l]   (D . V)
  float T[8][8];
#pragma unroll
  for (int k = 0; k < 8; ++k) {
#pragma unroll
    for (int l = 0; l < 8; ++l) {
      float s = 0.0f;
#pragma unroll
      for (int i = 0; i < 8; ++i) s = fmaf(DM[k][i], V[i][l], s);
      T[k][l] = s;
    }
  }

  const size_t obase = ((size_t)bc << 18) + (size_t)hb * 4096 + wb * 8;

  // ---- per band: Y_n = D . (M_n o T) . D^T  (exactly the reference einsum) ----
#pragma unroll
  for (int n = 0; n < 3; ++n) {
    // A[i][l] = sum_k DM[i][k] * W[k][l], W = masked T. band_of is constexpr
    // and n is unrolled -> zero terms are dead code (low/high: 16 coeffs).
    float A[8][8];
#pragma unroll
    for (int i = 0; i < 8; ++i) {
#pragma unroll
      for (int l = 0; l < 8; ++l) {
        float s = 0.0f;
#pragma unroll
        for (int k = 0; k < 8; ++k) {
          if (band_of(k, l) == n) s = fmaf(DM[i][k], T[k][l], s);
        }
        A[i][l] = s;
      }
    }
    float* o = out + (size_t)n * 25165824 + obase;  // band stride = 96*262144
#pragma unroll
    for (int i = 0; i < 8; ++i) {
      float y[8];
#pragma unroll
      for (int j = 0; j < 8; ++j) {
        float s = 0.0f;
#pragma unroll
        for (int l = 0; l < 8; ++l) s = fmaf(A[i][l], DM[j][l], s);
        y[j] = s;
      }
      *(float4*)(o + (size_t)i * 512)     = make_float4(y[0], y[1], y[2], y[3]);
      *(float4*)(o + (size_t)i * 512 + 4) = make_float4(y[4], y[5], y[6], y[7]);
    }
  }
}

extern "C" void kernel_launch(void* const* d_in, const int* in_sizes, int n_in,
                              void* d_out, int out_size, void* d_ws, size_t ws_size,
                              hipStream_t stream) {
  (void)in_sizes; (void)n_in; (void)d_ws; (void)ws_size; (void)out_size;
  const float* x = (const float*)d_in[0];
  float* out = (float*)d_out;
  // 32*3 images * 64*64 blocks = 393216 threads, exactly 1536 blocks of 256.
  const int total_threads = 32 * 3 * 64 * 64;
  freq_decomp_kernel<<<total_threads / 256, 256, 0, stream>>>(x, out);
}

// Round 2
// 371.335 us; speedup vs baseline: 1.0017x; 1.0017x over previous
//
#include <hip/hip_runtime.h>

// FrequencyDecomposition: blocked 8x8 DCT -> zigzag band masking -> blocked
// second transform (the reference einsum applies D . W . D^T again, NOT
// D^T W D -- we replicate the einsum exactly).
//
// x: [32, 3, 512, 512] fp32 -> out: [3, 32, 3, 512, 512] fp32
//
// v2: phase-interleaved to minimize live registers (v1 kept X,V,T,A = 256
// floats live -> spills/1-wave occupancy). Here each phase consumes its
// input as it produces output: peak live ~= T(64) + 3 A-rows(24) + y(24).
// Band masks fold at compile time: low band touches only output cols 0-5,
// high band only cols 2-7.

namespace {

constexpr float DM[8][8] = {
  { 0.35355339059327373f, 0.35355339059327373f, 0.35355339059327373f, 0.35355339059327373f,
    0.35355339059327373f, 0.35355339059327373f, 0.35355339059327373f, 0.35355339059327373f },
  { 0.49039264020161522f, 0.41573480615127262f, 0.27778511650980114f, 0.09754516100806417f,
   -0.09754516100806417f,-0.27778511650980114f,-0.41573480615127262f,-0.49039264020161522f },
  { 0.46193976625564337f, 0.19134171618254492f,-0.19134171618254492f,-0.46193976625564337f,
   -0.46193976625564337f,-0.19134171618254492f, 0.19134171618254492f, 0.46193976625564337f },
  { 0.41573480615127262f,-0.09754516100806417f,-0.49039264020161522f,-0.27778511650980114f,
    0.27778511650980114f, 0.49039264020161522f, 0.09754516100806417f,-0.41573480615127262f },
  { 0.35355339059327373f,-0.35355339059327373f,-0.35355339059327373f, 0.35355339059327373f,
    0.35355339059327373f,-0.35355339059327373f,-0.35355339059327373f, 0.35355339059327373f },
  { 0.27778511650980114f,-0.49039264020161522f, 0.09754516100806417f, 0.41573480615127262f,
   -0.41573480615127262f,-0.09754516100806417f, 0.49039264020161522f,-0.27778511650980114f },
  { 0.19134171618254492f,-0.46193976625564337f, 0.46193976625564337f,-0.19134171618254492f,
   -0.19134171618254492f, 0.46193976625564337f,-0.46193976625564337f, 0.19134171618254492f },
  { 0.09754516100806417f,-0.27778511650980114f, 0.41573480615127262f,-0.49039264020161522f,
    0.49039264020161522f,-0.41573480615127262f, 0.27778511650980114f,-0.09754516100806417f }
};

// Standard JPEG zigzag index of (k,l) -- matches reference _zigzag_indices.
constexpr int ZZ[8][8] = {
  { 0,  1,  5,  6, 14, 15, 27, 28},
  { 2,  4,  7, 13, 16, 26, 29, 42},
  { 3,  8, 12, 17, 25, 30, 41, 43},
  { 9, 11, 18, 24, 31, 40, 44, 53},
  {10, 19, 23, 32, 39, 45, 52, 54},
  {20, 22, 33, 38, 46, 51, 55, 60},
  {21, 34, 37, 47, 50, 56, 59, 61},
  {35, 36, 48, 49, 57, 58, 62, 63}
};

// band 0 = low (z < 16), band 2 = high (z >= 48), band 1 = mid.
constexpr int band_of(int k, int l) {
  return ZZ[k][l] < 16 ? 0 : (ZZ[k][l] >= 48 ? 2 : 1);
}

} // namespace

// x: [B=32, C=3, H=512, W=512]; 96 images of 512x512; 64x64 blocks per image.
__global__ __launch_bounds__(256, 3) void freq_decomp_kernel(
    const float* __restrict__ x, float* __restrict__ out) {
  const int tid = blockIdx.x * 256 + threadIdx.x;   // 0 .. 393215, exact grid
  const int wb = tid & 63;          // block col
  const int hb = (tid >> 6) & 63;   // block row
  const int bc = tid >> 12;         // image index 0..95

  const size_t base = ((size_t)bc << 18) + (size_t)hb * 4096 + (size_t)(wb * 8);
  const float* in = x + base;

  // ---- phase 1: load row r, immediately row-transform: V = X . D^T ----
  // X rows die as soon as they're consumed; only V (64) accumulates.
  float V[8][8];
#pragma unroll
  for (int r = 0; r < 8; ++r) {
    const float4 a = *(const float4*)(in + (size_t)r * 512);
    const float4 b = *(const float4*)(in + (size_t)r * 512 + 4);
    const float xr[8] = {a.x, a.y, a.z, a.w, b.x, b.y, b.z, b.w};
#pragma unroll
    for (int c = 0; c < 8; ++c) {
      float s = xr[0] * DM[c][0];
#pragma unroll
      for (int j = 1; j < 8; ++j) s = fmaf(xr[j], DM[c][j], s);
      V[r][c] = s;
    }
  }

  // ---- phase 2: T = D . V, column by column (V column dies per l) ----
  float T[8][8];
#pragma unroll
  for (int l = 0; l < 8; ++l) {
#pragma unroll
    for (int k = 0; k < 8; ++k) {
      float s = DM[k][0] * V[0][l];
#pragma unroll
      for (int i = 1; i < 8; ++i) s = fmaf(DM[k][i], V[i][l], s);
      T[k][l] = s;
    }
  }

  // ---- phase 3: per output row i, all three bands ----
  // Y_n = D . (M_n o T) . D^T, row i: A_n[l] = sum_k m_n DM[i][k] T[k][l],
  // y_n[j] = sum_l A_n[l] DM[j][l]. Masks are constexpr -> zero terms are
  // dead code. Low band: cols 0-5 only. High band: cols 2-7 only.
  float* const olow  = out + base;                   // band stride 96*512*512
  float* const omid  = olow + 25165824;
  float* const ohigh = omid + 25165824;

#pragma unroll
  for (int i = 0; i < 8; ++i) {
    float AL[8], AM[8], AH[8];
#pragma unroll
    for (int l = 0; l < 8; ++l) {
      float sl = 0.0f, sm = 0.0f, sh = 0.0f;
#pragma unroll
      for (int k = 0; k < 8; ++k) {
        const int b = band_of(k, l);
        if (b == 0) sl = fmaf(DM[i][k], T[k][l], sl);
        else if (b == 1) sm = fmaf(DM[i][k], T[k][l], sm);
        else sh = fmaf(DM[i][k], T[k][l], sh);
      }
      AL[l] = sl; AM[l] = sm; AH[l] = sh;
    }

    float yl[8], ym[8], yh[8];
#pragma unroll
    for (int j = 0; j < 8; ++j) {
      // low: cols 0..5 nonzero
      float s = AL[0] * DM[j][0];
#pragma unroll
      for (int l = 1; l < 6; ++l) s = fmaf(AL[l], DM[j][l], s);
      yl[j] = s;
      // mid: all cols
      float t = AM[0] * DM[j][0];
#pragma unroll
      for (int l = 1; l < 8; ++l) t = fmaf(AM[l], DM[j][l], t);
      ym[j] = t;
      // high: cols 2..7 nonzero
      float u = AH[2] * DM[j][2];
#pragma unroll
      for (int l = 3; l < 8; ++l) u = fmaf(AH[l], DM[j][l], u);
      yh[j] = u;
    }

    const size_t roff = (size_t)i * 512;
    *(float4*)(olow  + roff)     = make_float4(yl[0], yl[1], yl[2], yl[3]);
    *(float4*)(olow  + roff + 4) = make_float4(yl[4], yl[5], yl[6], yl[7]);
    *(float4*)(omid  + roff)     = make_float4(ym[0], ym[1], ym[2], ym[3]);
    *(float4*)(omid  + roff + 4) = make_float4(ym[4], ym[5], ym[6], ym[7]);
    *(float4*)(ohigh + roff)     = make_float4(yh[0], yh[1], yh[2], yh[3]);
    *(float4*)(ohigh + roff + 4) = make_float4(yh[4], yh[5], yh[6], yh[7]);
  }
}

extern "C" void kernel_launch(void* const* d_in, const int* in_sizes, int n_in,
                              void* d_out, int out_size, void* d_ws, size_t ws_size,
                              hipStream_t stream) {
  (void)in_sizes; (void)n_in; (void)d_ws; (void)ws_size; (void)out_size;
  const float* x = (const float*)d_in[0];
  float* out = (float*)d_out;
  // 32*3 images * 64*64 blocks = 393216 threads = 1536 blocks of 256.
  freq_decomp_kernel<<<1536, 256, 0, stream>>>(x, out);
}